// Round 1
// baseline (1085.608 us; speedup 1.0000x reference)
//
#include <hip/hip_runtime.h>
#include <hip/hip_bf16.h>
#include <math.h>
#include <stdint.h>

#define NB 8
#define NN 2048
#define DD 512
#define KN 3

#define BM 64
#define BN 64
#define BK 32

// ---------- Kernel A: row L2-normalize ----------
__global__ __launch_bounds__(256) void normalize_kernel(const float* __restrict__ feats,
                                                        float* __restrict__ xn) {
    int row  = blockIdx.x * 4 + (threadIdx.x >> 6);   // 4 waves/block, 1 row/wave
    int lane = threadIdx.x & 63;
    const float* src = feats + (size_t)row * DD + lane * 8;
    float4 v0 = *(const float4*)(src);
    float4 v1 = *(const float4*)(src + 4);
    float s = v0.x*v0.x + v0.y*v0.y + v0.z*v0.z + v0.w*v0.w
            + v1.x*v1.x + v1.y*v1.y + v1.z*v1.z + v1.w*v1.w;
    #pragma unroll
    for (int m = 32; m; m >>= 1) s += __shfl_xor(s, m, 64);
    float inv = 1.0f / fmaxf(sqrtf(s), 1e-12f);
    float* dst = xn + (size_t)row * DD + lane * 8;
    v0.x*=inv; v0.y*=inv; v0.z*=inv; v0.w*=inv;
    v1.x*=inv; v1.y*=inv; v1.z*=inv; v1.w*=inv;
    *(float4*)(dst)     = v0;
    *(float4*)(dst + 4) = v1;
}

// ---------- helpers for fused top-3 ----------
__device__ __forceinline__ unsigned int fkey(float v) {
    unsigned int b = __float_as_uint(v);
    // map float bits to monotonically increasing unsigned key
    return b ^ (((unsigned int)((int)b >> 31)) | 0x80000000u);
}
__device__ __forceinline__ void ins3(unsigned long long t3[3], unsigned long long pk) {
    if (pk > t3[0])      { t3[2] = t3[1]; t3[1] = t3[0]; t3[0] = pk; }
    else if (pk > t3[1]) { t3[2] = t3[1]; t3[1] = pk; }
    else if (pk > t3[2]) { t3[2] = pk; }
}

// ---------- Kernel B: fused  dis = xn@xn^T  +  per-row top-3 ----------
// grid: (N/BM, NB). Each block owns a 64-row strip and streams all 2048 cols.
__global__ __launch_bounds__(256, 1) void simtop_kernel(const float* __restrict__ xn,
                                                        int* __restrict__ idx_out) {
    __shared__ float As[BK][BM + 4];
    __shared__ float Bs[BK][BN + 4];

    const int b  = blockIdx.y;
    const int r0 = blockIdx.x * BM;
    const float* X = xn + (size_t)b * NN * DD;

    const int tid = threadIdx.x;
    const int tx  = tid & 15;        // col group (16)
    const int ty  = tid >> 4;        // row group (16)

    unsigned long long top[4][3];
    #pragma unroll
    for (int i = 0; i < 4; ++i)
        #pragma unroll
        for (int q = 0; q < 3; ++q) top[i][q] = 0ULL;   // acts as -inf sentinel

    for (int c0 = 0; c0 < NN; c0 += BN) {
        float acc[4][4];
        #pragma unroll
        for (int i = 0; i < 4; ++i)
            #pragma unroll
            for (int j = 0; j < 4; ++j) acc[i][j] = 0.0f;

        for (int k0 = 0; k0 < DD; k0 += BK) {
            #pragma unroll
            for (int t = 0; t < 2; ++t) {
                int li  = tid + t * 256;
                int row = li >> 3;
                int kc  = li & 7;
                float4 av = *(const float4*)(X + (size_t)(r0 + row) * DD + k0 + kc * 4);
                As[kc*4+0][row] = av.x; As[kc*4+1][row] = av.y;
                As[kc*4+2][row] = av.z; As[kc*4+3][row] = av.w;
                float4 bv = *(const float4*)(X + (size_t)(c0 + row) * DD + k0 + kc * 4);
                Bs[kc*4+0][row] = bv.x; Bs[kc*4+1][row] = bv.y;
                Bs[kc*4+2][row] = bv.z; Bs[kc*4+3][row] = bv.w;
            }
            __syncthreads();
            #pragma unroll
            for (int k = 0; k < BK; ++k) {
                float4 av = *(const float4*)&As[k][ty * 4];
                float4 bv = *(const float4*)&Bs[k][tx * 4];
                float a[4] = {av.x, av.y, av.z, av.w};
                float bb[4] = {bv.x, bv.y, bv.z, bv.w};
                #pragma unroll
                for (int i = 0; i < 4; ++i)
                    #pragma unroll
                    for (int j = 0; j < 4; ++j)
                        acc[i][j] = fmaf(a[i], bb[j], acc[i][j]);
            }
            __syncthreads();
        }

        // per-row top-3 of this 64-col tile, then merge into running top
        #pragma unroll
        for (int i = 0; i < 4; ++i) {
            unsigned long long t3[3] = {0ULL, 0ULL, 0ULL};
            #pragma unroll
            for (int j = 0; j < 4; ++j) {
                int col = c0 + tx * 4 + j;
                unsigned long long pk =
                    ((unsigned long long)fkey(acc[i][j]) << 32) |
                    (unsigned int)(NN - 1 - col);           // tie-break: lower col wins
                ins3(t3, pk);
            }
            #pragma unroll
            for (int m = 1; m < 16; m <<= 1) {
                unsigned long long o0 = __shfl_xor(t3[0], m, 64);
                unsigned long long o1 = __shfl_xor(t3[1], m, 64);
                unsigned long long o2 = __shfl_xor(t3[2], m, 64);
                ins3(t3, o0); ins3(t3, o1); ins3(t3, o2);
            }
            ins3(top[i], t3[0]); ins3(top[i], t3[1]); ins3(top[i], t3[2]);
        }
    }

    if (tx == 0) {
        #pragma unroll
        for (int i = 0; i < 4; ++i) {
            int row = r0 + ty * 4 + i;
            #pragma unroll
            for (int q = 0; q < 3; ++q)
                idx_out[((size_t)b * NN + row) * KN + q] =
                    (NN - 1) - (int)(top[i][q] & 0xFFFFFFFFu);
        }
    }
}

// ---------- Kernel C: gather + convKK + softmax + mean-pool ----------
// pooled[row] = sum_j c_j * knn_j,  c_j = (1/3) sum_g softmax_g[j]
__global__ __launch_bounds__(256) void convmap_kernel(const float* __restrict__ feats,
                                                      const float* __restrict__ w,
                                                      const float* __restrict__ bias,
                                                      const int* __restrict__ idx,
                                                      float* __restrict__ pooled) {
    int row  = blockIdx.x * 4 + (threadIdx.x >> 6);
    int lane = threadIdx.x & 63;
    int b    = row >> 11;                     // row / 2048
    const float* Fb = feats + (size_t)b * NN * DD;
    const int* ip   = idx + (size_t)row * KN;
    int nb0 = ip[0], nb1 = ip[1], nb2 = ip[2];

    float kn_v[KN][8];
    {
        const int nbs[KN] = {nb0, nb1, nb2};
        #pragma unroll
        for (int g = 0; g < KN; ++g) {
            const float* src = Fb + (size_t)nbs[g] * DD + lane * 8;
            float4 v0 = *(const float4*)(src);
            float4 v1 = *(const float4*)(src + 4);
            kn_v[g][0]=v0.x; kn_v[g][1]=v0.y; kn_v[g][2]=v0.z; kn_v[g][3]=v0.w;
            kn_v[g][4]=v1.x; kn_v[g][5]=v1.y; kn_v[g][6]=v1.z; kn_v[g][7]=v1.w;
        }
    }

    float p[KN][KN];
    #pragma unroll
    for (int g = 0; g < KN; ++g)
        #pragma unroll
        for (int j = 0; j < KN; ++j) {
            const float* wp = w + ((size_t)g * KN + j) * DD + lane * 8;
            float4 w0 = *(const float4*)(wp);
            float4 w1 = *(const float4*)(wp + 4);
            float s = kn_v[g][0]*w0.x + kn_v[g][1]*w0.y + kn_v[g][2]*w0.z + kn_v[g][3]*w0.w
                    + kn_v[g][4]*w1.x + kn_v[g][5]*w1.y + kn_v[g][6]*w1.z + kn_v[g][7]*w1.w;
            p[g][j] = s;
        }
    #pragma unroll
    for (int g = 0; g < KN; ++g)
        #pragma unroll
        for (int j = 0; j < KN; ++j)
            #pragma unroll
            for (int m = 32; m; m >>= 1) p[g][j] += __shfl_xor(p[g][j], m, 64);

    float c[KN] = {0.f, 0.f, 0.f};
    #pragma unroll
    for (int g = 0; g < KN; ++g) {
        float l0 = p[g][0] + bias[g*KN+0];
        float l1 = p[g][1] + bias[g*KN+1];
        float l2 = p[g][2] + bias[g*KN+2];
        float mx = fmaxf(l0, fmaxf(l1, l2));
        float e0 = expf(l0 - mx), e1 = expf(l1 - mx), e2 = expf(l2 - mx);
        float inv = 1.0f / (e0 + e1 + e2);
        c[0] += e0 * inv; c[1] += e1 * inv; c[2] += e2 * inv;
    }
    const float third = 1.0f / 3.0f;
    c[0] *= third; c[1] *= third; c[2] *= third;

    float* dst = pooled + (size_t)row * DD + lane * 8;
    float4 o0, o1;
    o0.x = c[0]*kn_v[0][0] + c[1]*kn_v[1][0] + c[2]*kn_v[2][0];
    o0.y = c[0]*kn_v[0][1] + c[1]*kn_v[1][1] + c[2]*kn_v[2][1];
    o0.z = c[0]*kn_v[0][2] + c[1]*kn_v[1][2] + c[2]*kn_v[2][2];
    o0.w = c[0]*kn_v[0][3] + c[1]*kn_v[1][3] + c[2]*kn_v[2][3];
    o1.x = c[0]*kn_v[0][4] + c[1]*kn_v[1][4] + c[2]*kn_v[2][4];
    o1.y = c[0]*kn_v[0][5] + c[1]*kn_v[1][5] + c[2]*kn_v[2][5];
    o1.z = c[0]*kn_v[0][6] + c[1]*kn_v[1][6] + c[2]*kn_v[2][6];
    o1.w = c[0]*kn_v[0][7] + c[1]*kn_v[1][7] + c[2]*kn_v[2][7];
    *(float4*)(dst)     = o0;
    *(float4*)(dst + 4) = o1;
}

// ---------- Kernel D: out = relu(pooled @ fc_w^T) ----------
// grid: (M/BM, 512/BN)
__global__ __launch_bounds__(256, 1) void fc_relu_kernel(const float* __restrict__ A,
                                                         const float* __restrict__ Bm,
                                                         float* __restrict__ out) {
    __shared__ float As[BK][BM + 4];
    __shared__ float Bs[BK][BN + 4];

    const int r0 = blockIdx.x * BM;
    const int c0 = blockIdx.y * BN;
    const int tid = threadIdx.x;
    const int tx  = tid & 15;
    const int ty  = tid >> 4;

    float acc[4][4];
    #pragma unroll
    for (int i = 0; i < 4; ++i)
        #pragma unroll
        for (int j = 0; j < 4; ++j) acc[i][j] = 0.0f;

    for (int k0 = 0; k0 < DD; k0 += BK) {
        #pragma unroll
        for (int t = 0; t < 2; ++t) {
            int li  = tid + t * 256;
            int row = li >> 3;
            int kc  = li & 7;
            float4 av = *(const float4*)(A + (size_t)(r0 + row) * DD + k0 + kc * 4);
            As[kc*4+0][row] = av.x; As[kc*4+1][row] = av.y;
            As[kc*4+2][row] = av.z; As[kc*4+3][row] = av.w;
            float4 bv = *(const float4*)(Bm + (size_t)(c0 + row) * DD + k0 + kc * 4);
            Bs[kc*4+0][row] = bv.x; Bs[kc*4+1][row] = bv.y;
            Bs[kc*4+2][row] = bv.z; Bs[kc*4+3][row] = bv.w;
        }
        __syncthreads();
        #pragma unroll
        for (int k = 0; k < BK; ++k) {
            float4 av = *(const float4*)&As[k][ty * 4];
            float4 bv = *(const float4*)&Bs[k][tx * 4];
            float a[4] = {av.x, av.y, av.z, av.w};
            float bb[4] = {bv.x, bv.y, bv.z, bv.w};
            #pragma unroll
            for (int i = 0; i < 4; ++i)
                #pragma unroll
                for (int j = 0; j < 4; ++j)
                    acc[i][j] = fmaf(a[i], bb[j], acc[i][j]);
        }
        __syncthreads();
    }

    #pragma unroll
    for (int i = 0; i < 4; ++i) {
        float4 o;
        o.x = fmaxf(acc[i][0], 0.f);
        o.y = fmaxf(acc[i][1], 0.f);
        o.z = fmaxf(acc[i][2], 0.f);
        o.w = fmaxf(acc[i][3], 0.f);
        *(float4*)(out + (size_t)(r0 + ty * 4 + i) * 512 + c0 + tx * 4) = o;
    }
}

extern "C" void kernel_launch(void* const* d_in, const int* in_sizes, int n_in,
                              void* d_out, int out_size, void* d_ws, size_t ws_size,
                              hipStream_t stream) {
    const float* feats    = (const float*)d_in[0];   // (8,2048,512)
    const float* convKK_w = (const float*)d_in[1];   // (3,3,512)
    const float* convKK_b = (const float*)d_in[2];   // (3,3)
    const float* fc_w     = (const float*)d_in[3];   // (512,512)
    float* out = (float*)d_out;                      // (8,2048,512)

    float* xn     = (float*)d_ws;                         // 8*2048*512 f32
    int*   idx    = (int*)(xn + (size_t)NB * NN * DD);    // 16384*3 i32
    float* pooled = (float*)(idx + (size_t)NB * NN * KN); // 16384*512 f32

    const int ROWS = NB * NN; // 16384

    normalize_kernel<<<ROWS / 4, 256, 0, stream>>>(feats, xn);

    dim3 gB(NN / BM, NB);
    simtop_kernel<<<gB, 256, 0, stream>>>(xn, idx);

    convmap_kernel<<<ROWS / 4, 256, 0, stream>>>(feats, convKK_w, convKK_b, idx, pooled);

    dim3 gD(ROWS / BM, 512 / BN);
    fc_relu_kernel<<<gD, 256, 0, stream>>>(pooled, fc_w, out);
}

// Round 3
// 409.466 us; speedup vs baseline: 2.6513x; 2.6513x over previous
//
#include <hip/hip_runtime.h>
#include <hip/hip_bf16.h>
#include <math.h>
#include <stdint.h>

#define NB 8
#define NN 2048
#define DD 512
#define KN 3

// simtop geometry
#define BR 128          // rows per block (N-dim of mfma, the "top-k query" rows)
#define BC 128          // cols per tile (M-dim of mfma, the candidate cols)
#define SBK 32          // K-step
#define SPLITS 4        // col splits -> 512 blocks
#define PADK 40         // 32 + 8 pad (ushort elems) -> 80B row stride, 2-way banks (free)

typedef unsigned long long u64;
typedef unsigned short ushort_t;
typedef __attribute__((ext_vector_type(8))) short short8v;   // 8 bf16 = 4 VGPR
typedef __attribute__((ext_vector_type(4))) float floatx4;   // mfma accumulator

// key of -INF: fkey(0xFF800000) = ~0xFF800000 = 0x007FFFFF  (decodes back to -INF, not NaN)
#define NEGINF_KEY (((u64)0x007FFFFFu) << 32)

// ---------- float <-> sortable key helpers ----------
__device__ __forceinline__ unsigned int fkey(float v) {
    unsigned int b = __float_as_uint(v);
    return b ^ (((unsigned int)((int)b >> 31)) | 0x80000000u);
}
__device__ __forceinline__ float unfkey(unsigned int k) {
    unsigned int b = (k & 0x80000000u) ? (k ^ 0x80000000u) : ~k;
    return __uint_as_float(b);
}
__device__ __forceinline__ unsigned short bf16_rne(float x) {
    unsigned int u = __float_as_uint(x);
    unsigned int r = u + 0x7FFFu + ((u >> 16) & 1u);
    return (unsigned short)(r >> 16);
}
__device__ __forceinline__ void ins3(u64 t3[3], u64 pk) {
    if (pk > t3[0])      { t3[2] = t3[1]; t3[1] = t3[0]; t3[0] = pk; }
    else if (pk > t3[1]) { t3[2] = t3[1]; t3[1] = pk; }
    else if (pk > t3[2]) { t3[2] = pk; }
}
__device__ __forceinline__ void ins4(u64 t[4], u64 pk) {
    if (pk > t[0])      { t[3]=t[2]; t[2]=t[1]; t[1]=t[0]; t[0]=pk; }
    else if (pk > t[1]) { t[3]=t[2]; t[2]=t[1]; t[1]=pk; }
    else if (pk > t[2]) { t[3]=t[2]; t[2]=pk; }
    else if (pk > t[3]) { t[3]=pk; }
}

// ---------- Kernel 1: prep — norms + hi/lo bf16 split of normalized rows ----------
__global__ __launch_bounds__(256) void prep_kernel(const float* __restrict__ feats,
                                                   ushort_t* __restrict__ xh,
                                                   ushort_t* __restrict__ xl,
                                                   float* __restrict__ norms) {
    int row  = blockIdx.x * 4 + (threadIdx.x >> 6);
    int lane = threadIdx.x & 63;
    const float* src = feats + (size_t)row * DD + lane * 8;
    float4 v0 = *(const float4*)(src);
    float4 v1 = *(const float4*)(src + 4);
    float s = v0.x*v0.x + v0.y*v0.y + v0.z*v0.z + v0.w*v0.w
            + v1.x*v1.x + v1.y*v1.y + v1.z*v1.z + v1.w*v1.w;
    #pragma unroll
    for (int m = 32; m; m >>= 1) s += __shfl_xor(s, m, 64);
    float nrm = fmaxf(sqrtf(s), 1e-12f);
    float inv = 1.0f / nrm;
    if (lane == 0) norms[row] = nrm;

    float e[8] = {v0.x, v0.y, v0.z, v0.w, v1.x, v1.y, v1.z, v1.w};
    unsigned int hw[4], lw[4];
    #pragma unroll
    for (int p = 0; p < 4; ++p) {
        float x0 = e[2*p]   * inv;
        float x1 = e[2*p+1] * inv;
        unsigned short h0 = bf16_rne(x0), h1 = bf16_rne(x1);
        float l0f = x0 - __uint_as_float(((unsigned int)h0) << 16);
        float l1f = x1 - __uint_as_float(((unsigned int)h1) << 16);
        unsigned short s0 = bf16_rne(l0f), s1 = bf16_rne(l1f);
        hw[p] = (unsigned int)h0 | ((unsigned int)h1 << 16);
        lw[p] = (unsigned int)s0 | ((unsigned int)s1 << 16);
    }
    uint4 hv = {hw[0], hw[1], hw[2], hw[3]};
    uint4 lv = {lw[0], lw[1], lw[2], lw[3]};
    *(uint4*)(xh + (size_t)row * DD + lane * 8) = hv;
    *(uint4*)(xl + (size_t)row * DD + lane * 8) = lv;
}

// ---------- Kernel 2: simtop — bf16 hi/lo split MFMA GEMM + per-row approx top-4 ----------
// Computes D[col][row] (transposed) so top-k candidates are lane-local.
// grid: (16384/BR, SPLITS)
__global__ __launch_bounds__(256) void simtop_kernel(const ushort_t* __restrict__ xh,
                                                     const ushort_t* __restrict__ xl,
                                                     u64* __restrict__ cand) {
    // tiles: [0]=colsHi [1]=colsLo [2]=rowsHi [3]=rowsLo
    __shared__ ushort_t tiles[4][BR][PADK];   // 40960 B

    const int tid   = threadIdx.x;
    const int strip = blockIdx.x;             // 0..127
    const int split = blockIdx.y;             // 0..3
    const int R0    = strip * BR;             // global row base (batch-aligned: 128|2048)
    const int b     = R0 >> 11;
    const size_t bbase = (size_t)b * NN;      // global row idx of batch start
    const int lane = tid & 63, half = lane >> 4, l15 = lane & 15;
    const int wid = tid >> 6, wm = wid & 1, wn = wid >> 1;

    // staging role (fixed per thread): which of the 4 LDS arrays this thread fills
    const int arr = tid >> 6;                 // 0..3
    const int lt  = tid & 63;
    const ushort_t* sbase = (arr & 1) ? xl : xh;

    u64 t4[4][4];
    float t4v[4];
    #pragma unroll
    for (int r = 0; r < 4; ++r) {
        t4v[r] = -INFINITY;
        #pragma unroll
        for (int q = 0; q < 4; ++q) t4[r][q] = NEGINF_KEY;  // decodes to -INF, never NaN
    }

    for (int t = 0; t < (NN / SPLITS) / BC; ++t) {     // 4 col tiles of 128
        const int c0 = split * (NN / SPLITS) + t * BC; // within-batch col base
        const size_t rowbase = (arr < 2) ? (bbase + (size_t)c0) : (size_t)R0;

        floatx4 acc[4][4];
        #pragma unroll
        for (int mc = 0; mc < 4; ++mc)
            #pragma unroll
            for (int nr = 0; nr < 4; ++nr)
                acc[mc][nr] = (floatx4){0.f, 0.f, 0.f, 0.f};

        for (int k0 = 0; k0 < DD; k0 += SBK) {
            // ---- stage: each thread copies 8x16B chunks of its array ----
            #pragma unroll
            for (int j = 0; j < 8; ++j) {
                int c   = lt + 64 * j;        // chunk 0..511
                int row = c >> 2, q = c & 3;
                uint4 v = *(const uint4*)(sbase + (rowbase + row) * DD + k0 + q * 8);
                *(uint4*)&tiles[arr][row][q * 8] = v;
            }
            __syncthreads();
            // ---- compute ----
            short8v ah[4], al[4];
            #pragma unroll
            for (int mc = 0; mc < 4; ++mc) {
                int r = wm * 64 + mc * 16 + l15;
                ah[mc] = *(const short8v*)&tiles[0][r][half * 8];
                al[mc] = *(const short8v*)&tiles[1][r][half * 8];
            }
            #pragma unroll
            for (int nr = 0; nr < 4; ++nr) {
                int r = wn * 64 + nr * 16 + l15;
                short8v bh = *(const short8v*)&tiles[2][r][half * 8];
                short8v bl = *(const short8v*)&tiles[3][r][half * 8];
                #pragma unroll
                for (int mc = 0; mc < 4; ++mc) {
                    acc[mc][nr] = __builtin_amdgcn_mfma_f32_16x16x32_bf16(ah[mc], bh, acc[mc][nr], 0, 0, 0);
                    acc[mc][nr] = __builtin_amdgcn_mfma_f32_16x16x32_bf16(ah[mc], bl, acc[mc][nr], 0, 0, 0);
                    acc[mc][nr] = __builtin_amdgcn_mfma_f32_16x16x32_bf16(al[mc], bh, acc[mc][nr], 0, 0, 0);
                }
            }
            __syncthreads();
        }

        // ---- lane-local top-4 scan (threshold-guarded, inserts are rare) ----
        #pragma unroll
        for (int nr = 0; nr < 4; ++nr) {
            #pragma unroll
            for (int mc = 0; mc < 4; ++mc) {
                #pragma unroll
                for (int i = 0; i < 4; ++i) {
                    float v = acc[mc][nr][i];
                    if (v >= t4v[nr]) {
                        int col = c0 + wm * 64 + mc * 16 + half * 4 + i;
                        u64 pk = ((u64)fkey(v) << 32) | (unsigned int)(NN - 1 - col);
                        ins4(t4[nr], pk);
                        t4v[nr] = unfkey((unsigned int)(t4[nr][3] >> 32));
                    }
                }
            }
        }
    }

    // ---- block-end merge of the 8 partial lists per row via LDS ----
    __syncthreads();
    u64* mlds = (u64*)&tiles[0][0][0];       // 128 rows x 8 lists x 4 keys = 32 KB
    #pragma unroll
    for (int nr = 0; nr < 4; ++nr) {
        int rl   = wn * 64 + nr * 16 + l15;
        int list = wm * 4 + half;
        #pragma unroll
        for (int q = 0; q < 4; ++q) mlds[(rl * 8 + list) * 4 + q] = t4[nr][q];
    }
    __syncthreads();
    if (tid < BR) {
        u64 best[4] = {0ULL, 0ULL, 0ULL, 0ULL};
        #pragma unroll 4
        for (int j = 0; j < 32; ++j) ins4(best, mlds[tid * 32 + j]);
        size_t grow = (size_t)(R0 + tid);
        #pragma unroll
        for (int q = 0; q < 4; ++q)
            cand[(grow * SPLITS + split) * 4 + q] = best[q];
    }
}

// ---------- Kernel 3: refine — exact fp32 re-rank of 16 candidates -> top-3 idx ----------
__global__ __launch_bounds__(256) void refine_kernel(const float* __restrict__ feats,
                                                     const float* __restrict__ norms,
                                                     const u64* __restrict__ cand,
                                                     int* __restrict__ idx) {
    int grow = blockIdx.x * 4 + (threadIdx.x >> 6);
    int lane = threadIdx.x & 63;
    int b    = grow >> 11;
    const float* Fb = feats + (size_t)b * NN * DD;
    int n = grow & (NN - 1);
    const float* qp = Fb + (size_t)n * DD + lane * 8;
    float4 q0 = *(const float4*)(qp);
    float4 q1 = *(const float4*)(qp + 4);
    float inv_nq = 1.0f / norms[grow];

    u64 t3[3] = {0ULL, 0ULL, 0ULL};
    for (int c = 0; c < SPLITS * 4; ++c) {
        u64 pk0 = cand[(size_t)grow * (SPLITS * 4) + c];
        int col = (NN - 1) - (int)(pk0 & 0xFFFFFFFFu);
        const float* xc = Fb + (size_t)col * DD + lane * 8;
        float4 c0 = *(const float4*)(xc);
        float4 c1 = *(const float4*)(xc + 4);
        float s = q0.x*c0.x + q0.y*c0.y + q0.z*c0.z + q0.w*c0.w
                + q1.x*c1.x + q1.y*c1.y + q1.z*c1.z + q1.w*c1.w;
        #pragma unroll
        for (int m = 32; m; m >>= 1) s += __shfl_xor(s, m, 64);
        float sim = s * inv_nq / norms[(size_t)b * NN + col];
        u64 pk = ((u64)fkey(sim) << 32) | (unsigned int)(NN - 1 - col);
        ins3(t3, pk);
    }
    if (lane == 0) {
        #pragma unroll
        for (int q = 0; q < 3; ++q)
            idx[(size_t)grow * KN + q] = (NN - 1) - (int)(t3[q] & 0xFFFFFFFFu);
    }
}

// ---------- Kernel 4: gather + convKK + softmax + mean-pool ----------
__global__ __launch_bounds__(256) void convmap_kernel(const float* __restrict__ feats,
                                                      const float* __restrict__ w,
                                                      const float* __restrict__ bias,
                                                      const int* __restrict__ idx,
                                                      float* __restrict__ pooled) {
    int row  = blockIdx.x * 4 + (threadIdx.x >> 6);
    int lane = threadIdx.x & 63;
    int b    = row >> 11;
    const float* Fb = feats + (size_t)b * NN * DD;
    const int* ip   = idx + (size_t)row * KN;
    int nb0 = ip[0], nb1 = ip[1], nb2 = ip[2];

    float kn_v[KN][8];
    {
        const int nbs[KN] = {nb0, nb1, nb2};
        #pragma unroll
        for (int g = 0; g < KN; ++g) {
            const float* src = Fb + (size_t)nbs[g] * DD + lane * 8;
            float4 v0 = *(const float4*)(src);
            float4 v1 = *(const float4*)(src + 4);
            kn_v[g][0]=v0.x; kn_v[g][1]=v0.y; kn_v[g][2]=v0.z; kn_v[g][3]=v0.w;
            kn_v[g][4]=v1.x; kn_v[g][5]=v1.y; kn_v[g][6]=v1.z; kn_v[g][7]=v1.w;
        }
    }

    float p[KN][KN];
    #pragma unroll
    for (int g = 0; g < KN; ++g)
        #pragma unroll
        for (int j = 0; j < KN; ++j) {
            const float* wp = w + ((size_t)g * KN + j) * DD + lane * 8;
            float4 w0 = *(const float4*)(wp);
            float4 w1 = *(const float4*)(wp + 4);
            float s = kn_v[g][0]*w0.x + kn_v[g][1]*w0.y + kn_v[g][2]*w0.z + kn_v[g][3]*w0.w
                    + kn_v[g][4]*w1.x + kn_v[g][5]*w1.y + kn_v[g][6]*w1.z + kn_v[g][7]*w1.w;
            p[g][j] = s;
        }
    #pragma unroll
    for (int g = 0; g < KN; ++g)
        #pragma unroll
        for (int j = 0; j < KN; ++j)
            #pragma unroll
            for (int m = 32; m; m >>= 1) p[g][j] += __shfl_xor(p[g][j], m, 64);

    float c[KN] = {0.f, 0.f, 0.f};
    #pragma unroll
    for (int g = 0; g < KN; ++g) {
        float l0 = p[g][0] + bias[g*KN+0];
        float l1 = p[g][1] + bias[g*KN+1];
        float l2 = p[g][2] + bias[g*KN+2];
        float mx = fmaxf(l0, fmaxf(l1, l2));
        float e0 = expf(l0 - mx), e1 = expf(l1 - mx), e2 = expf(l2 - mx);
        float inv = 1.0f / (e0 + e1 + e2);
        c[0] += e0 * inv; c[1] += e1 * inv; c[2] += e2 * inv;
    }
    const float third = 1.0f / 3.0f;
    c[0] *= third; c[1] *= third; c[2] *= third;

    float* dst = pooled + (size_t)row * DD + lane * 8;
    float4 o0, o1;
    o0.x = c[0]*kn_v[0][0] + c[1]*kn_v[1][0] + c[2]*kn_v[2][0];
    o0.y = c[0]*kn_v[0][1] + c[1]*kn_v[1][1] + c[2]*kn_v[2][1];
    o0.z = c[0]*kn_v[0][2] + c[1]*kn_v[1][2] + c[2]*kn_v[2][2];
    o0.w = c[0]*kn_v[0][3] + c[1]*kn_v[1][3] + c[2]*kn_v[2][3];
    o1.x = c[0]*kn_v[0][4] + c[1]*kn_v[1][4] + c[2]*kn_v[2][4];
    o1.y = c[0]*kn_v[0][5] + c[1]*kn_v[1][5] + c[2]*kn_v[2][5];
    o1.z = c[0]*kn_v[0][6] + c[1]*kn_v[1][6] + c[2]*kn_v[2][6];
    o1.w = c[0]*kn_v[0][7] + c[1]*kn_v[1][7] + c[2]*kn_v[2][7];
    *(float4*)(dst)     = o0;
    *(float4*)(dst + 4) = o1;
}

// ---------- Kernel 5: out = relu(pooled @ fc_w^T) ----------
#define FBM 64
#define FBN 64
#define FBK 32
__global__ __launch_bounds__(256, 1) void fc_relu_kernel(const float* __restrict__ A,
                                                         const float* __restrict__ Bm,
                                                         float* __restrict__ out) {
    __shared__ float As[FBK][FBM + 4];
    __shared__ float Bs[FBK][FBN + 4];

    const int r0 = blockIdx.x * FBM;
    const int c0 = blockIdx.y * FBN;
    const int tid = threadIdx.x;
    const int tx  = tid & 15;
    const int ty  = tid >> 4;

    float acc[4][4];
    #pragma unroll
    for (int i = 0; i < 4; ++i)
        #pragma unroll
        for (int j = 0; j < 4; ++j) acc[i][j] = 0.0f;

    for (int k0 = 0; k0 < DD; k0 += FBK) {
        #pragma unroll
        for (int t = 0; t < 2; ++t) {
            int li  = tid + t * 256;
            int row = li >> 3;
            int kc  = li & 7;
            float4 av = *(const float4*)(A + (size_t)(r0 + row) * DD + k0 + kc * 4);
            As[kc*4+0][row] = av.x; As[kc*4+1][row] = av.y;
            As[kc*4+2][row] = av.z; As[kc*4+3][row] = av.w;
            float4 bv = *(const float4*)(Bm + (size_t)(c0 + row) * DD + k0 + kc * 4);
            Bs[kc*4+0][row] = bv.x; Bs[kc*4+1][row] = bv.y;
            Bs[kc*4+2][row] = bv.z; Bs[kc*4+3][row] = bv.w;
        }
        __syncthreads();
        #pragma unroll
        for (int k = 0; k < FBK; ++k) {
            float4 av = *(const float4*)&As[k][ty * 4];
            float4 bv = *(const float4*)&Bs[k][tx * 4];
            float a[4] = {av.x, av.y, av.z, av.w};
            float bb[4] = {bv.x, bv.y, bv.z, bv.w};
            #pragma unroll
            for (int i = 0; i < 4; ++i)
                #pragma unroll
                for (int j = 0; j < 4; ++j)
                    acc[i][j] = fmaf(a[i], bb[j], acc[i][j]);
        }
        __syncthreads();
    }

    #pragma unroll
    for (int i = 0; i < 4; ++i) {
        float4 o;
        o.x = fmaxf(acc[i][0], 0.f);
        o.y = fmaxf(acc[i][1], 0.f);
        o.z = fmaxf(acc[i][2], 0.f);
        o.w = fmaxf(acc[i][3], 0.f);
        *(float4*)(out + (size_t)(r0 + ty * 4 + i) * 512 + c0 + tx * 4) = o;
    }
}

extern "C" void kernel_launch(void* const* d_in, const int* in_sizes, int n_in,
                              void* d_out, int out_size, void* d_ws, size_t ws_size,
                              hipStream_t stream) {
    const float* feats    = (const float*)d_in[0];   // (8,2048,512)
    const float* convKK_w = (const float*)d_in[1];   // (3,3,512)
    const float* convKK_b = (const float*)d_in[2];   // (3,3)
    const float* fc_w     = (const float*)d_in[3];   // (512,512)
    float* out = (float*)d_out;                      // (8,2048,512)

    const int ROWS = NB * NN;                        // 16384

    // workspace layout (35.9 MB total):
    // [xh bf16 16.78M][xl bf16 16.78M][norms 64K][cand 2.1M][idx 0.2M]
    // pooled aliases xh+xl (dead after simtop; refine uses feats+norms).
    ushort_t* xh = (ushort_t*)d_ws;
    ushort_t* xl = xh + (size_t)ROWS * DD;
    float* norms = (float*)(xl + (size_t)ROWS * DD);
    u64* cand    = (u64*)(norms + ROWS);
    int* idx     = (int*)(cand + (size_t)ROWS * SPLITS * 4);
    float* pooled = (float*)d_ws;                    // alias

    prep_kernel<<<ROWS / 4, 256, 0, stream>>>(feats, xh, xl, norms);

    dim3 gS(ROWS / BR, SPLITS);
    simtop_kernel<<<gS, 256, 0, stream>>>(xh, xl, cand);

    refine_kernel<<<ROWS / 4, 256, 0, stream>>>(feats, norms, cand, idx);

    convmap_kernel<<<ROWS / 4, 256, 0, stream>>>(feats, convKK_w, convKK_b, idx, pooled);

    dim3 gD(ROWS / FBM, 512 / FBN);
    fc_relu_kernel<<<gD, 256, 0, stream>>>(pooled, fc_w, out);
}

// Round 4
// 346.549 us; speedup vs baseline: 3.1326x; 1.1816x over previous
//
#include <hip/hip_runtime.h>
#include <hip/hip_bf16.h>
#include <math.h>
#include <stdint.h>

#define NB 8
#define NN 2048
#define DD 512
#define KN 3

// simtop geometry
#define BR 128          // rows per block (queries)
#define BC 128          // cols per tile (candidates)
#define SBK 32          // K-step
#define SPLITS 8        // col splits -> 1024 blocks = 4/CU (LDS 40960B*4 = exactly 160KiB)
#define PADK 40         // 32 + 8 pad (ushort) -> 80B row stride, 2-way banks (free, m136)

typedef unsigned long long u64;
typedef unsigned short ushort_t;
typedef __attribute__((ext_vector_type(8))) short short8v;   // 8 bf16 = 4 VGPR
typedef __attribute__((ext_vector_type(4))) float floatx4;   // mfma accumulator

// key of -INF: fkey(0xFF800000) = 0x007FFFFF (decodes back to -INF, not NaN)
#define NEGINF_KEY (((u64)0x007FFFFFu) << 32)

// ---------- float <-> sortable key helpers ----------
__device__ __forceinline__ unsigned int fkey(float v) {
    unsigned int b = __float_as_uint(v);
    return b ^ (((unsigned int)((int)b >> 31)) | 0x80000000u);
}
__device__ __forceinline__ float unfkey(unsigned int k) {
    unsigned int b = (k & 0x80000000u) ? (k ^ 0x80000000u) : ~k;
    return __uint_as_float(b);
}
__device__ __forceinline__ unsigned short bf16_rne(float x) {
    unsigned int u = __float_as_uint(x);
    unsigned int r = u + 0x7FFFu + ((u >> 16) & 1u);
    return (unsigned short)(r >> 16);
}
__device__ __forceinline__ void ins3(u64 t3[3], u64 pk) {
    if (pk > t3[0])      { t3[2] = t3[1]; t3[1] = t3[0]; t3[0] = pk; }
    else if (pk > t3[1]) { t3[2] = t3[1]; t3[1] = pk; }
    else if (pk > t3[2]) { t3[2] = pk; }
}
__device__ __forceinline__ void ins4(u64 t[4], u64 pk) {
    if (pk > t[0])      { t[3]=t[2]; t[2]=t[1]; t[1]=t[0]; t[0]=pk; }
    else if (pk > t[1]) { t[3]=t[2]; t[2]=t[1]; t[1]=pk; }
    else if (pk > t[2]) { t[3]=t[2]; t[2]=pk; }
    else if (pk > t[3]) { t[3]=pk; }
}

// ---------- Kernel 1: prep — norms + hi/lo bf16 split of normalized rows ----------
__global__ __launch_bounds__(256) void prep_kernel(const float* __restrict__ feats,
                                                   ushort_t* __restrict__ xh,
                                                   ushort_t* __restrict__ xl,
                                                   float* __restrict__ norms) {
    int row  = blockIdx.x * 4 + (threadIdx.x >> 6);
    int lane = threadIdx.x & 63;
    const float* src = feats + (size_t)row * DD + lane * 8;
    float4 v0 = *(const float4*)(src);
    float4 v1 = *(const float4*)(src + 4);
    float s = v0.x*v0.x + v0.y*v0.y + v0.z*v0.z + v0.w*v0.w
            + v1.x*v1.x + v1.y*v1.y + v1.z*v1.z + v1.w*v1.w;
    #pragma unroll
    for (int m = 32; m; m >>= 1) s += __shfl_xor(s, m, 64);
    float nrm = fmaxf(sqrtf(s), 1e-12f);
    float inv = 1.0f / nrm;
    if (lane == 0) norms[row] = nrm;

    float e[8] = {v0.x, v0.y, v0.z, v0.w, v1.x, v1.y, v1.z, v1.w};
    unsigned int hw[4], lw[4];
    #pragma unroll
    for (int p = 0; p < 4; ++p) {
        float x0 = e[2*p]   * inv;
        float x1 = e[2*p+1] * inv;
        unsigned short h0 = bf16_rne(x0), h1 = bf16_rne(x1);
        float l0f = x0 - __uint_as_float(((unsigned int)h0) << 16);
        float l1f = x1 - __uint_as_float(((unsigned int)h1) << 16);
        unsigned short s0 = bf16_rne(l0f), s1 = bf16_rne(l1f);
        hw[p] = (unsigned int)h0 | ((unsigned int)h1 << 16);
        lw[p] = (unsigned int)s0 | ((unsigned int)s1 << 16);
    }
    uint4 hv = {hw[0], hw[1], hw[2], hw[3]};
    uint4 lv = {lw[0], lw[1], lw[2], lw[3]};
    *(uint4*)(xh + (size_t)row * DD + lane * 8) = hv;
    *(uint4*)(xl + (size_t)row * DD + lane * 8) = lv;
}

// ---------- Kernel 1b: fc_w fp32 -> bf16 ----------
__global__ __launch_bounds__(256) void prepw_kernel(const float* __restrict__ w,
                                                    ushort_t* __restrict__ wb) {
    int i = (blockIdx.x * 256 + threadIdx.x) * 8;
    float4 v0 = *(const float4*)(w + i);
    float4 v1 = *(const float4*)(w + i + 4);
    float e[8] = {v0.x, v0.y, v0.z, v0.w, v1.x, v1.y, v1.z, v1.w};
    unsigned int o[4];
    #pragma unroll
    for (int p = 0; p < 4; ++p)
        o[p] = (unsigned int)bf16_rne(e[2*p]) | ((unsigned int)bf16_rne(e[2*p+1]) << 16);
    uint4 ov = {o[0], o[1], o[2], o[3]};
    *(uint4*)(wb + i) = ov;
}

// ---------- Kernel 2: simtop — bf16 hi/lo split MFMA GEMM + per-row approx top-4 ----------
// Computes D[col][row] (transposed) so top-k candidates are lane-local.
// grid: (16384/BR, SPLITS)
__global__ __launch_bounds__(256) void simtop_kernel(const ushort_t* __restrict__ xh,
                                                     const ushort_t* __restrict__ xl,
                                                     u64* __restrict__ cand) {
    // tiles: [0]=colsHi [1]=colsLo [2]=rowsHi [3]=rowsLo
    __shared__ ushort_t tiles[4][BR][PADK];   // 40960 B

    const int tid   = threadIdx.x;
    const int strip = blockIdx.x;             // 0..127
    const int split = blockIdx.y;             // 0..SPLITS-1
    const int R0    = strip * BR;             // global row base (batch-aligned: 128|2048)
    const int b     = R0 >> 11;
    const size_t bbase = (size_t)b * NN;
    const int lane = tid & 63, half = lane >> 4, l15 = lane & 15;
    const int wid = tid >> 6, wm = wid & 1, wn = wid >> 1;

    const int arr = tid >> 6;                 // staging role: which LDS array
    const int lt  = tid & 63;
    const ushort_t* sbase = (arr & 1) ? xl : xh;

    u64 t4[4][4];
    float t4v[4];
    #pragma unroll
    for (int r = 0; r < 4; ++r) {
        t4v[r] = -INFINITY;
        #pragma unroll
        for (int q = 0; q < 4; ++q) t4[r][q] = NEGINF_KEY;
    }

    for (int t = 0; t < (NN / SPLITS) / BC; ++t) {     // 2 col tiles of 128
        const int c0 = split * (NN / SPLITS) + t * BC;
        const size_t rowbase = (arr < 2) ? (bbase + (size_t)c0) : (size_t)R0;

        floatx4 acc[4][4];
        #pragma unroll
        for (int mc = 0; mc < 4; ++mc)
            #pragma unroll
            for (int nr = 0; nr < 4; ++nr)
                acc[mc][nr] = (floatx4){0.f, 0.f, 0.f, 0.f};

        for (int k0 = 0; k0 < DD; k0 += SBK) {
            #pragma unroll
            for (int j = 0; j < 8; ++j) {
                int c   = lt + 64 * j;
                int row = c >> 2, q = c & 3;
                uint4 v = *(const uint4*)(sbase + (rowbase + row) * DD + k0 + q * 8);
                *(uint4*)&tiles[arr][row][q * 8] = v;
            }
            __syncthreads();
            short8v ah[4], al[4];
            #pragma unroll
            for (int mc = 0; mc < 4; ++mc) {
                int r = wm * 64 + mc * 16 + l15;
                ah[mc] = *(const short8v*)&tiles[0][r][half * 8];
                al[mc] = *(const short8v*)&tiles[1][r][half * 8];
            }
            #pragma unroll
            for (int nr = 0; nr < 4; ++nr) {
                int r = wn * 64 + nr * 16 + l15;
                short8v bh = *(const short8v*)&tiles[2][r][half * 8];
                short8v bl = *(const short8v*)&tiles[3][r][half * 8];
                #pragma unroll
                for (int mc = 0; mc < 4; ++mc) {
                    acc[mc][nr] = __builtin_amdgcn_mfma_f32_16x16x32_bf16(ah[mc], bh, acc[mc][nr], 0, 0, 0);
                    acc[mc][nr] = __builtin_amdgcn_mfma_f32_16x16x32_bf16(ah[mc], bl, acc[mc][nr], 0, 0, 0);
                    acc[mc][nr] = __builtin_amdgcn_mfma_f32_16x16x32_bf16(al[mc], bh, acc[mc][nr], 0, 0, 0);
                }
            }
            __syncthreads();
        }

        #pragma unroll
        for (int nr = 0; nr < 4; ++nr) {
            #pragma unroll
            for (int mc = 0; mc < 4; ++mc) {
                #pragma unroll
                for (int i = 0; i < 4; ++i) {
                    float v = acc[mc][nr][i];
                    if (v >= t4v[nr]) {
                        int col = c0 + wm * 64 + mc * 16 + half * 4 + i;
                        u64 pk = ((u64)fkey(v) << 32) | (unsigned int)(NN - 1 - col);
                        ins4(t4[nr], pk);
                        t4v[nr] = unfkey((unsigned int)(t4[nr][3] >> 32));
                    }
                }
            }
        }
    }

    // ---- block-end merge of the 8 partial lists per row via LDS ----
    __syncthreads();
    u64* mlds = (u64*)&tiles[0][0][0];       // 128 rows x 8 lists x 4 keys = 32 KB
    #pragma unroll
    for (int nr = 0; nr < 4; ++nr) {
        int rl   = wn * 64 + nr * 16 + l15;
        int list = wm * 4 + half;
        #pragma unroll
        for (int q = 0; q < 4; ++q) mlds[(rl * 8 + list) * 4 + q] = t4[nr][q];
    }
    __syncthreads();
    if (tid < BR) {
        u64 best[4] = {0ULL, 0ULL, 0ULL, 0ULL};
        #pragma unroll 4
        for (int j = 0; j < 32; ++j) ins4(best, mlds[tid * 32 + j]);
        size_t grow = (size_t)(R0 + tid);
        #pragma unroll
        for (int q = 0; q < 4; ++q)
            cand[(grow * SPLITS + split) * 4 + q] = best[q];
    }
}

// ---------- Kernel 3: refine — exact fp32 re-rank of 32 candidates -> top-3 idx ----------
__global__ __launch_bounds__(256) void refine_kernel(const float* __restrict__ feats,
                                                     const float* __restrict__ norms,
                                                     const u64* __restrict__ cand,
                                                     int* __restrict__ idx) {
    int grow = blockIdx.x * 4 + (threadIdx.x >> 6);
    int lane = threadIdx.x & 63;
    int b    = grow >> 11;
    const float* Fb = feats + (size_t)b * NN * DD;
    int n = grow & (NN - 1);
    const float* qp = Fb + (size_t)n * DD + lane * 8;
    float4 q0 = *(const float4*)(qp);
    float4 q1 = *(const float4*)(qp + 4);
    float inv_nq = 1.0f / norms[grow];

    u64 t3[3] = {0ULL, 0ULL, 0ULL};
    for (int c = 0; c < SPLITS * 4; ++c) {
        u64 pk0 = cand[(size_t)grow * (SPLITS * 4) + c];
        int col = (NN - 1) - (int)(pk0 & 0xFFFFFFFFu);
        const float* xc = Fb + (size_t)col * DD + lane * 8;
        float4 c0 = *(const float4*)(xc);
        float4 c1 = *(const float4*)(xc + 4);
        float s = q0.x*c0.x + q0.y*c0.y + q0.z*c0.z + q0.w*c0.w
                + q1.x*c1.x + q1.y*c1.y + q1.z*c1.z + q1.w*c1.w;
        #pragma unroll
        for (int m = 32; m; m >>= 1) s += __shfl_xor(s, m, 64);
        float sim = s * inv_nq / norms[(size_t)b * NN + col];
        u64 pk = ((u64)fkey(sim) << 32) | (unsigned int)(NN - 1 - col);
        ins3(t3, pk);
    }
    if (lane == 0) {
        #pragma unroll
        for (int q = 0; q < 3; ++q)
            idx[(size_t)grow * KN + q] = (NN - 1) - (int)(t3[q] & 0xFFFFFFFFu);
    }
}

// ---------- Kernel 4: gather + convKK + softmax + mean-pool -> pooled (bf16) ----------
__global__ __launch_bounds__(256) void convmap_kernel(const float* __restrict__ feats,
                                                      const float* __restrict__ w,
                                                      const float* __restrict__ bias,
                                                      const int* __restrict__ idx,
                                                      ushort_t* __restrict__ pooled_b) {
    int row  = blockIdx.x * 4 + (threadIdx.x >> 6);
    int lane = threadIdx.x & 63;
    int b    = row >> 11;
    const float* Fb = feats + (size_t)b * NN * DD;
    const int* ip   = idx + (size_t)row * KN;
    int nb0 = ip[0], nb1 = ip[1], nb2 = ip[2];

    float kn_v[KN][8];
    {
        const int nbs[KN] = {nb0, nb1, nb2};
        #pragma unroll
        for (int g = 0; g < KN; ++g) {
            const float* src = Fb + (size_t)nbs[g] * DD + lane * 8;
            float4 v0 = *(const float4*)(src);
            float4 v1 = *(const float4*)(src + 4);
            kn_v[g][0]=v0.x; kn_v[g][1]=v0.y; kn_v[g][2]=v0.z; kn_v[g][3]=v0.w;
            kn_v[g][4]=v1.x; kn_v[g][5]=v1.y; kn_v[g][6]=v1.z; kn_v[g][7]=v1.w;
        }
    }

    float p[KN][KN];
    #pragma unroll
    for (int g = 0; g < KN; ++g)
        #pragma unroll
        for (int j = 0; j < KN; ++j) {
            const float* wp = w + ((size_t)g * KN + j) * DD + lane * 8;
            float4 w0 = *(const float4*)(wp);
            float4 w1 = *(const float4*)(wp + 4);
            float s = kn_v[g][0]*w0.x + kn_v[g][1]*w0.y + kn_v[g][2]*w0.z + kn_v[g][3]*w0.w
                    + kn_v[g][4]*w1.x + kn_v[g][5]*w1.y + kn_v[g][6]*w1.z + kn_v[g][7]*w1.w;
            p[g][j] = s;
        }
    #pragma unroll
    for (int g = 0; g < KN; ++g)
        #pragma unroll
        for (int j = 0; j < KN; ++j)
            #pragma unroll
            for (int m = 32; m; m >>= 1) p[g][j] += __shfl_xor(p[g][j], m, 64);

    float c[KN] = {0.f, 0.f, 0.f};
    #pragma unroll
    for (int g = 0; g < KN; ++g) {
        float l0 = p[g][0] + bias[g*KN+0];
        float l1 = p[g][1] + bias[g*KN+1];
        float l2 = p[g][2] + bias[g*KN+2];
        float mx = fmaxf(l0, fmaxf(l1, l2));
        float e0 = expf(l0 - mx), e1 = expf(l1 - mx), e2 = expf(l2 - mx);
        float inv = 1.0f / (e0 + e1 + e2);
        c[0] += e0 * inv; c[1] += e1 * inv; c[2] += e2 * inv;
    }
    const float third = 1.0f / 3.0f;
    c[0] *= third; c[1] *= third; c[2] *= third;

    unsigned int o[4];
    #pragma unroll
    for (int p2 = 0; p2 < 4; ++p2) {
        float a = c[0]*kn_v[0][2*p2]   + c[1]*kn_v[1][2*p2]   + c[2]*kn_v[2][2*p2];
        float d = c[0]*kn_v[0][2*p2+1] + c[1]*kn_v[1][2*p2+1] + c[2]*kn_v[2][2*p2+1];
        o[p2] = (unsigned int)bf16_rne(a) | ((unsigned int)bf16_rne(d) << 16);
    }
    uint4 ov = {o[0], o[1], o[2], o[3]};
    *(uint4*)(pooled_b + (size_t)row * DD + lane * 8) = ov;
}

// ---------- Kernel 5: out = relu(pooled_b @ fcw_b^T), bf16 MFMA ----------
// A-tile = fc_w rows (out cols), B-tile = pooled rows; D[col][row] like simtop.
// grid: (16384/128, 512/128)
__global__ __launch_bounds__(256) void fc_mfma_kernel(const ushort_t* __restrict__ fcw_b,
                                                      const ushort_t* __restrict__ pooled_b,
                                                      float* __restrict__ out) {
    __shared__ ushort_t at[BR][PADK];   // fc_w tile  (cols)
    __shared__ ushort_t bt[BR][PADK];   // pooled tile (rows)

    const int tid = threadIdx.x;
    const int R0  = blockIdx.x * 128;   // pooled row base
    const int c0  = blockIdx.y * 128;   // out col base
    const int lane = tid & 63, half = lane >> 4, l15 = lane & 15;
    const int wid = tid >> 6, wm = wid & 1, wn = wid >> 1;

    const int arr = tid >> 7;           // 0: at, 1: bt
    const int lt  = tid & 127;
    const ushort_t* src = arr ? pooled_b : fcw_b;
    const size_t rowbase = arr ? (size_t)R0 : (size_t)c0;

    floatx4 acc[4][4];
    #pragma unroll
    for (int mc = 0; mc < 4; ++mc)
        #pragma unroll
        for (int nr = 0; nr < 4; ++nr)
            acc[mc][nr] = (floatx4){0.f, 0.f, 0.f, 0.f};

    for (int k0 = 0; k0 < DD; k0 += SBK) {
        #pragma unroll
        for (int j = 0; j < 4; ++j) {
            int c   = lt + 128 * j;
            int row = c >> 2, q = c & 3;
            uint4 v = *(const uint4*)(src + (rowbase + row) * DD + k0 + q * 8);
            ushort_t (*tile)[PADK] = arr ? bt : at;
            *(uint4*)&tile[row][q * 8] = v;
        }
        __syncthreads();
        short8v a[4], bfr[4];
        #pragma unroll
        for (int mc = 0; mc < 4; ++mc)
            a[mc] = *(const short8v*)&at[wm * 64 + mc * 16 + l15][half * 8];
        #pragma unroll
        for (int nr = 0; nr < 4; ++nr)
            bfr[nr] = *(const short8v*)&bt[wn * 64 + nr * 16 + l15][half * 8];
        #pragma unroll
        for (int nr = 0; nr < 4; ++nr)
            #pragma unroll
            for (int mc = 0; mc < 4; ++mc)
                acc[mc][nr] = __builtin_amdgcn_mfma_f32_16x16x32_bf16(a[mc], bfr[nr], acc[mc][nr], 0, 0, 0);
        __syncthreads();
    }

    #pragma unroll
    for (int nr = 0; nr < 4; ++nr) {
        int prow = R0 + wn * 64 + nr * 16 + l15;
        #pragma unroll
        for (int mc = 0; mc < 4; ++mc) {
            int colb = c0 + wm * 64 + mc * 16 + half * 4;
            float4 o;
            o.x = fmaxf(acc[mc][nr][0], 0.f);
            o.y = fmaxf(acc[mc][nr][1], 0.f);
            o.z = fmaxf(acc[mc][nr][2], 0.f);
            o.w = fmaxf(acc[mc][nr][3], 0.f);
            *(float4*)(out + (size_t)prow * 512 + colb) = o;
        }
    }
}

extern "C" void kernel_launch(void* const* d_in, const int* in_sizes, int n_in,
                              void* d_out, int out_size, void* d_ws, size_t ws_size,
                              hipStream_t stream) {
    const float* feats    = (const float*)d_in[0];   // (8,2048,512)
    const float* convKK_w = (const float*)d_in[1];   // (3,3,512)
    const float* convKK_b = (const float*)d_in[2];   // (3,3)
    const float* fc_w     = (const float*)d_in[3];   // (512,512)
    float* out = (float*)d_out;                      // (8,2048,512)

    const int ROWS = NB * NN;                        // 16384

    // workspace (~38.5 MB):
    // [xh 16.78M][xl 16.78M][norms 64K][cand 4.19M][idx 196K][fcw_b 512K]
    // pooled_b aliases xh (dead after simtop; refine reads feats+norms+cand).
    ushort_t* xh = (ushort_t*)d_ws;
    ushort_t* xl = xh + (size_t)ROWS * DD;
    float* norms = (float*)(xl + (size_t)ROWS * DD);
    u64* cand    = (u64*)(norms + ROWS);
    int* idx     = (int*)(cand + (size_t)ROWS * SPLITS * 4);
    ushort_t* fcw_b = (ushort_t*)(idx + (size_t)ROWS * KN);
    ushort_t* pooled_b = xh;                         // alias

    prep_kernel<<<ROWS / 4, 256, 0, stream>>>(feats, xh, xl, norms);
    prepw_kernel<<<(512 * 512) / (256 * 8), 256, 0, stream>>>(fc_w, fcw_b);

    dim3 gS(ROWS / BR, SPLITS);
    simtop_kernel<<<gS, 256, 0, stream>>>(xh, xl, cand);

    refine_kernel<<<ROWS / 4, 256, 0, stream>>>(feats, norms, cand, idx);

    convmap_kernel<<<ROWS / 4, 256, 0, stream>>>(feats, convKK_w, convKK_b, idx, pooled_b);

    dim3 gF(ROWS / 128, 512 / 128);
    fc_mfma_kernel<<<gF, 256, 0, stream>>>(fcw_b, pooled_b, out);
}

// Round 5
// 292.252 us; speedup vs baseline: 3.7146x; 1.1858x over previous
//
#include <hip/hip_runtime.h>
#include <hip/hip_bf16.h>
#include <math.h>
#include <stdint.h>

#define NB 8
#define NN 2048
#define DD 512
#define KN 3

// simtop geometry
#define BR 128          // rows per block (queries)
#define BC 128          // cols per tile (candidates)
#define SBK 32          // K-step
#define SPLITS 8        // col splits; split == XCD (blockIdx.x & 7 round-robin)
#define PADK 40         // 32 + 8 pad (ushort) -> 80B row stride, ~2-way banks (free, m136)

typedef unsigned long long u64;
typedef unsigned short ushort_t;
typedef __attribute__((ext_vector_type(8))) short short8v;   // 8 bf16 = 4 VGPR
typedef __attribute__((ext_vector_type(4))) float floatx4;   // mfma accumulator

// key of -INF: fkey(0xFF800000) = 0x007FFFFF (decodes back to -INF, not NaN)
#define NEGINF_KEY (((u64)0x007FFFFFu) << 32)

// ---------- float <-> sortable key helpers ----------
__device__ __forceinline__ unsigned int fkey(float v) {
    unsigned int b = __float_as_uint(v);
    return b ^ (((unsigned int)((int)b >> 31)) | 0x80000000u);
}
__device__ __forceinline__ float unfkey(unsigned int k) {
    unsigned int b = (k & 0x80000000u) ? (k ^ 0x80000000u) : ~k;
    return __uint_as_float(b);
}
__device__ __forceinline__ unsigned short bf16_rne(float x) {
    unsigned int u = __float_as_uint(x);
    unsigned int r = u + 0x7FFFu + ((u >> 16) & 1u);
    return (unsigned short)(r >> 16);
}
__device__ __forceinline__ void ins3(u64 t3[3], u64 pk) {
    if (pk > t3[0])      { t3[2] = t3[1]; t3[1] = t3[0]; t3[0] = pk; }
    else if (pk > t3[1]) { t3[2] = t3[1]; t3[1] = pk; }
    else if (pk > t3[2]) { t3[2] = pk; }
}
__device__ __forceinline__ void ins4(u64 t[4], u64 pk) {
    if (pk > t[0])      { t[3]=t[2]; t[2]=t[1]; t[1]=t[0]; t[0]=pk; }
    else if (pk > t[1]) { t[3]=t[2]; t[2]=t[1]; t[1]=pk; }
    else if (pk > t[2]) { t[3]=t[2]; t[2]=pk; }
    else if (pk > t[3]) { t[3]=pk; }
}

// ---------- Kernel 1: prep — norms + bf16 of normalized rows ----------
__global__ __launch_bounds__(256) void prep_kernel(const float* __restrict__ feats,
                                                   ushort_t* __restrict__ xh,
                                                   float* __restrict__ norms) {
    int row  = blockIdx.x * 4 + (threadIdx.x >> 6);
    int lane = threadIdx.x & 63;
    const float* src = feats + (size_t)row * DD + lane * 8;
    float4 v0 = *(const float4*)(src);
    float4 v1 = *(const float4*)(src + 4);
    float s = v0.x*v0.x + v0.y*v0.y + v0.z*v0.z + v0.w*v0.w
            + v1.x*v1.x + v1.y*v1.y + v1.z*v1.z + v1.w*v1.w;
    #pragma unroll
    for (int m = 32; m; m >>= 1) s += __shfl_xor(s, m, 64);
    float nrm = fmaxf(sqrtf(s), 1e-12f);
    float inv = 1.0f / nrm;
    if (lane == 0) norms[row] = nrm;

    float e[8] = {v0.x, v0.y, v0.z, v0.w, v1.x, v1.y, v1.z, v1.w};
    unsigned int hw[4];
    #pragma unroll
    for (int p = 0; p < 4; ++p)
        hw[p] = (unsigned int)bf16_rne(e[2*p] * inv)
              | ((unsigned int)bf16_rne(e[2*p+1] * inv) << 16);
    uint4 hv = {hw[0], hw[1], hw[2], hw[3]};
    *(uint4*)(xh + (size_t)row * DD + lane * 8) = hv;
}

// ---------- Kernel 1b: fc_w fp32 -> bf16 ----------
__global__ __launch_bounds__(256) void prepw_kernel(const float* __restrict__ w,
                                                    ushort_t* __restrict__ wb) {
    int i = (blockIdx.x * 256 + threadIdx.x) * 8;
    float4 v0 = *(const float4*)(w + i);
    float4 v1 = *(const float4*)(w + i + 4);
    float e[8] = {v0.x, v0.y, v0.z, v0.w, v1.x, v1.y, v1.z, v1.w};
    unsigned int o[4];
    #pragma unroll
    for (int p = 0; p < 4; ++p)
        o[p] = (unsigned int)bf16_rne(e[2*p]) | ((unsigned int)bf16_rne(e[2*p+1]) << 16);
    uint4 ov = {o[0], o[1], o[2], o[3]};
    *(uint4*)(wb + i) = ov;
}

// ---------- Kernel 2: simtop — single bf16 MFMA GEMM + per-row approx top-4 ----------
// D[col][row] (swapped operands) so top-k candidates are lane-local.
// grid: 1024 1D; split = bid&7 (== XCD), strip = bid>>3. Exact refine downstream
// absorbs the bf16 ranking noise (~1.5e-4 std vs ~5e-3 tail gaps).
__global__ __launch_bounds__(256) void simtop_kernel(const ushort_t* __restrict__ xh,
                                                     u64* __restrict__ cand) {
    // tiles[0]=cols, tiles[1]=rows(queries). 20480 B; merge scratch (8KB) aliases.
    __shared__ ushort_t tiles[2][BR][PADK];

    const int tid   = threadIdx.x;
    const int split = blockIdx.x & 7;         // XCD-resident split (L2 locality)
    const int strip = blockIdx.x >> 3;        // 0..127
    const int R0    = strip * BR;             // global row base (batch-aligned)
    const int b     = R0 >> 11;
    const size_t bbase = (size_t)b * NN;
    const int lane = tid & 63, half = lane >> 4, l15 = lane & 15;
    const int wid = tid >> 6, wm = wid & 1, wn = wid >> 1;

    const int arr = tid >> 7;                 // staging role: 0=cols, 1=queries
    const int lt  = tid & 127;

    u64 t4[4][4];
    float t4v[4];
    #pragma unroll
    for (int r = 0; r < 4; ++r) {
        t4v[r] = -INFINITY;
        #pragma unroll
        for (int q = 0; q < 4; ++q) t4[r][q] = NEGINF_KEY;
    }

    for (int t = 0; t < (NN / SPLITS) / BC; ++t) {     // 2 col tiles of 128
        const int c0 = split * (NN / SPLITS) + t * BC;
        const size_t rowbase = (arr == 0) ? (bbase + (size_t)c0) : (size_t)R0;

        floatx4 acc[4][4];
        #pragma unroll
        for (int mc = 0; mc < 4; ++mc)
            #pragma unroll
            for (int nr = 0; nr < 4; ++nr)
                acc[mc][nr] = (floatx4){0.f, 0.f, 0.f, 0.f};

        for (int k0 = 0; k0 < DD; k0 += SBK) {
            #pragma unroll
            for (int j = 0; j < 4; ++j) {
                int c   = lt + 128 * j;       // chunk 0..511
                int row = c >> 2, q = c & 3;
                uint4 v = *(const uint4*)(xh + (rowbase + row) * DD + k0 + q * 8);
                *(uint4*)&tiles[arr][row][q * 8] = v;
            }
            __syncthreads();
            short8v a[4], bq[4];
            #pragma unroll
            for (int mc = 0; mc < 4; ++mc)
                a[mc] = *(const short8v*)&tiles[0][wm * 64 + mc * 16 + l15][half * 8];
            #pragma unroll
            for (int nr = 0; nr < 4; ++nr)
                bq[nr] = *(const short8v*)&tiles[1][wn * 64 + nr * 16 + l15][half * 8];
            #pragma unroll
            for (int nr = 0; nr < 4; ++nr)
                #pragma unroll
                for (int mc = 0; mc < 4; ++mc)
                    acc[mc][nr] = __builtin_amdgcn_mfma_f32_16x16x32_bf16(a[mc], bq[nr], acc[mc][nr], 0, 0, 0);
            __syncthreads();
        }

        // lane-local top-4 scan (threshold-guarded, inserts are rare)
        #pragma unroll
        for (int nr = 0; nr < 4; ++nr) {
            #pragma unroll
            for (int mc = 0; mc < 4; ++mc) {
                #pragma unroll
                for (int i = 0; i < 4; ++i) {
                    float v = acc[mc][nr][i];
                    if (v >= t4v[nr]) {
                        int col = c0 + wm * 64 + mc * 16 + half * 4 + i;
                        u64 pk = ((u64)fkey(v) << 32) | (unsigned int)(NN - 1 - col);
                        ins4(t4[nr], pk);
                        t4v[nr] = unfkey((unsigned int)(t4[nr][3] >> 32));
                    }
                }
            }
        }
    }

    // ---- in-wave merge across the 4 'half' col-groups (shfl, no LDS) ----
    #pragma unroll
    for (int nr = 0; nr < 4; ++nr) {
        #pragma unroll
        for (int m = 16; m <= 32; m <<= 1) {
            u64 o0 = __shfl_xor(t4[nr][0], m, 64);
            u64 o1 = __shfl_xor(t4[nr][1], m, 64);
            u64 o2 = __shfl_xor(t4[nr][2], m, 64);
            u64 o3 = __shfl_xor(t4[nr][3], m, 64);
            ins4(t4[nr], o0); ins4(t4[nr], o1); ins4(t4[nr], o2); ins4(t4[nr], o3);
        }
    }
    // ---- cross-wave merge via LDS: 128 rows x 2 lists (wm) x 4 keys = 8 KB ----
    u64* mlds = (u64*)&tiles[0][0][0];
    if (half == 0) {
        #pragma unroll
        for (int nr = 0; nr < 4; ++nr) {
            int rl = wn * 64 + nr * 16 + l15;
            #pragma unroll
            for (int q = 0; q < 4; ++q) mlds[(rl * 2 + wm) * 4 + q] = t4[nr][q];
        }
    }
    __syncthreads();
    if (tid < BR) {
        u64 best[4] = {0ULL, 0ULL, 0ULL, 0ULL};
        #pragma unroll
        for (int j = 0; j < 8; ++j) ins4(best, mlds[tid * 8 + j]);
        size_t grow = (size_t)(R0 + tid);
        #pragma unroll
        for (int q = 0; q < 4; ++q)
            cand[(grow * SPLITS + split) * 4 + q] = best[q];
    }
}

// ---------- Kernel 3: refine — exact fp32 re-rank of 32 candidates -> top-3 idx ----------
__global__ __launch_bounds__(256) void refine_kernel(const float* __restrict__ feats,
                                                     const float* __restrict__ norms,
                                                     const u64* __restrict__ cand,
                                                     int* __restrict__ idx) {
    int grow = blockIdx.x * 4 + (threadIdx.x >> 6);
    int lane = threadIdx.x & 63;
    int b    = grow >> 11;
    const float* Fb = feats + (size_t)b * NN * DD;
    int n = grow & (NN - 1);
    const float* qp = Fb + (size_t)n * DD + lane * 8;
    float4 q0 = *(const float4*)(qp);
    float4 q1 = *(const float4*)(qp + 4);
    float inv_nq = 1.0f / norms[grow];

    u64 t3[3] = {0ULL, 0ULL, 0ULL};
    for (int c = 0; c < SPLITS * 4; ++c) {
        u64 pk0 = cand[(size_t)grow * (SPLITS * 4) + c];
        int col = (NN - 1) - (int)(pk0 & 0xFFFFFFFFu);
        const float* xc = Fb + (size_t)col * DD + lane * 8;
        float4 c0 = *(const float4*)(xc);
        float4 c1 = *(const float4*)(xc + 4);
        float s = q0.x*c0.x + q0.y*c0.y + q0.z*c0.z + q0.w*c0.w
                + q1.x*c1.x + q1.y*c1.y + q1.z*c1.z + q1.w*c1.w;
        #pragma unroll
        for (int m = 32; m; m >>= 1) s += __shfl_xor(s, m, 64);
        float sim = s * inv_nq / norms[(size_t)b * NN + col];
        u64 pk = ((u64)fkey(sim) << 32) | (unsigned int)(NN - 1 - col);
        ins3(t3, pk);
    }
    if (lane == 0) {
        #pragma unroll
        for (int q = 0; q < 3; ++q)
            idx[(size_t)grow * KN + q] = (NN - 1) - (int)(t3[q] & 0xFFFFFFFFu);
    }
}

// ---------- Kernel 4: gather + convKK + softmax + mean-pool -> pooled (bf16) ----------
__global__ __launch_bounds__(256) void convmap_kernel(const float* __restrict__ feats,
                                                      const float* __restrict__ w,
                                                      const float* __restrict__ bias,
                                                      const int* __restrict__ idx,
                                                      ushort_t* __restrict__ pooled_b) {
    int row  = blockIdx.x * 4 + (threadIdx.x >> 6);
    int lane = threadIdx.x & 63;
    int b    = row >> 11;
    const float* Fb = feats + (size_t)b * NN * DD;
    const int* ip   = idx + (size_t)row * KN;
    int nb0 = ip[0], nb1 = ip[1], nb2 = ip[2];

    float kn_v[KN][8];
    {
        const int nbs[KN] = {nb0, nb1, nb2};
        #pragma unroll
        for (int g = 0; g < KN; ++g) {
            const float* src = Fb + (size_t)nbs[g] * DD + lane * 8;
            float4 v0 = *(const float4*)(src);
            float4 v1 = *(const float4*)(src + 4);
            kn_v[g][0]=v0.x; kn_v[g][1]=v0.y; kn_v[g][2]=v0.z; kn_v[g][3]=v0.w;
            kn_v[g][4]=v1.x; kn_v[g][5]=v1.y; kn_v[g][6]=v1.z; kn_v[g][7]=v1.w;
        }
    }

    float p[KN][KN];
    #pragma unroll
    for (int g = 0; g < KN; ++g)
        #pragma unroll
        for (int j = 0; j < KN; ++j) {
            const float* wp = w + ((size_t)g * KN + j) * DD + lane * 8;
            float4 w0 = *(const float4*)(wp);
            float4 w1 = *(const float4*)(wp + 4);
            float s = kn_v[g][0]*w0.x + kn_v[g][1]*w0.y + kn_v[g][2]*w0.z + kn_v[g][3]*w0.w
                    + kn_v[g][4]*w1.x + kn_v[g][5]*w1.y + kn_v[g][6]*w1.z + kn_v[g][7]*w1.w;
            p[g][j] = s;
        }
    #pragma unroll
    for (int g = 0; g < KN; ++g)
        #pragma unroll
        for (int j = 0; j < KN; ++j)
            #pragma unroll
            for (int m = 32; m; m >>= 1) p[g][j] += __shfl_xor(p[g][j], m, 64);

    float c[KN] = {0.f, 0.f, 0.f};
    #pragma unroll
    for (int g = 0; g < KN; ++g) {
        float l0 = p[g][0] + bias[g*KN+0];
        float l1 = p[g][1] + bias[g*KN+1];
        float l2 = p[g][2] + bias[g*KN+2];
        float mx = fmaxf(l0, fmaxf(l1, l2));
        float e0 = expf(l0 - mx), e1 = expf(l1 - mx), e2 = expf(l2 - mx);
        float inv = 1.0f / (e0 + e1 + e2);
        c[0] += e0 * inv; c[1] += e1 * inv; c[2] += e2 * inv;
    }
    const float third = 1.0f / 3.0f;
    c[0] *= third; c[1] *= third; c[2] *= third;

    unsigned int o[4];
    #pragma unroll
    for (int p2 = 0; p2 < 4; ++p2) {
        float a = c[0]*kn_v[0][2*p2]   + c[1]*kn_v[1][2*p2]   + c[2]*kn_v[2][2*p2];
        float d = c[0]*kn_v[0][2*p2+1] + c[1]*kn_v[1][2*p2+1] + c[2]*kn_v[2][2*p2+1];
        o[p2] = (unsigned int)bf16_rne(a) | ((unsigned int)bf16_rne(d) << 16);
    }
    uint4 ov = {o[0], o[1], o[2], o[3]};
    *(uint4*)(pooled_b + (size_t)row * DD + lane * 8) = ov;
}

// ---------- Kernel 5: out = relu(pooled_b @ fcw_b^T), bf16 MFMA ----------
__global__ __launch_bounds__(256) void fc_mfma_kernel(const ushort_t* __restrict__ fcw_b,
                                                      const ushort_t* __restrict__ pooled_b,
                                                      float* __restrict__ out) {
    __shared__ ushort_t at[BR][PADK];   // fc_w tile  (out cols)
    __shared__ ushort_t bt[BR][PADK];   // pooled tile (rows)

    const int tid = threadIdx.x;
    const int R0  = blockIdx.x * 128;   // pooled row base
    const int c0  = blockIdx.y * 128;   // out col base
    const int lane = tid & 63, half = lane >> 4, l15 = lane & 15;
    const int wid = tid >> 6, wm = wid & 1, wn = wid >> 1;

    const int arr = tid >> 7;           // 0: at, 1: bt
    const int lt  = tid & 127;
    const ushort_t* src = arr ? pooled_b : fcw_b;
    const size_t rowbase = arr ? (size_t)R0 : (size_t)c0;

    floatx4 acc[4][4];
    #pragma unroll
    for (int mc = 0; mc < 4; ++mc)
        #pragma unroll
        for (int nr = 0; nr < 4; ++nr)
            acc[mc][nr] = (floatx4){0.f, 0.f, 0.f, 0.f};

    for (int k0 = 0; k0 < DD; k0 += SBK) {
        #pragma unroll
        for (int j = 0; j < 4; ++j) {
            int c   = lt + 128 * j;
            int row = c >> 2, q = c & 3;
            uint4 v = *(const uint4*)(src + (rowbase + row) * DD + k0 + q * 8);
            ushort_t (*tile)[PADK] = arr ? bt : at;
            *(uint4*)&tile[row][q * 8] = v;
        }
        __syncthreads();
        short8v a[4], bfr[4];
        #pragma unroll
        for (int mc = 0; mc < 4; ++mc)
            a[mc] = *(const short8v*)&at[wm * 64 + mc * 16 + l15][half * 8];
        #pragma unroll
        for (int nr = 0; nr < 4; ++nr)
            bfr[nr] = *(const short8v*)&bt[wn * 64 + nr * 16 + l15][half * 8];
        #pragma unroll
        for (int nr = 0; nr < 4; ++nr)
            #pragma unroll
            for (int mc = 0; mc < 4; ++mc)
                acc[mc][nr] = __builtin_amdgcn_mfma_f32_16x16x32_bf16(a[mc], bfr[nr], acc[mc][nr], 0, 0, 0);
        __syncthreads();
    }

    #pragma unroll
    for (int nr = 0; nr < 4; ++nr) {
        int prow = R0 + wn * 64 + nr * 16 + l15;
        #pragma unroll
        for (int mc = 0; mc < 4; ++mc) {
            int colb = c0 + wm * 64 + mc * 16 + half * 4;
            float4 o;
            o.x = fmaxf(acc[mc][nr][0], 0.f);
            o.y = fmaxf(acc[mc][nr][1], 0.f);
            o.z = fmaxf(acc[mc][nr][2], 0.f);
            o.w = fmaxf(acc[mc][nr][3], 0.f);
            *(float4*)(out + (size_t)prow * 512 + colb) = o;
        }
    }
}

extern "C" void kernel_launch(void* const* d_in, const int* in_sizes, int n_in,
                              void* d_out, int out_size, void* d_ws, size_t ws_size,
                              hipStream_t stream) {
    const float* feats    = (const float*)d_in[0];   // (8,2048,512)
    const float* convKK_w = (const float*)d_in[1];   // (3,3,512)
    const float* convKK_b = (const float*)d_in[2];   // (3,3)
    const float* fc_w     = (const float*)d_in[3];   // (512,512)
    float* out = (float*)d_out;                      // (8,2048,512)

    const int ROWS = NB * NN;                        // 16384

    // workspace (~21.7 MB): [xh 16.78M][norms 64K][cand 4.19M][idx 196K][fcw_b 512K]
    // pooled_b aliases xh (dead after simtop; refine reads feats+norms+cand).
    ushort_t* xh = (ushort_t*)d_ws;
    float* norms = (float*)(xh + (size_t)ROWS * DD);
    u64* cand    = (u64*)(norms + ROWS);
    int* idx     = (int*)(cand + (size_t)ROWS * SPLITS * 4);
    ushort_t* fcw_b = (ushort_t*)(idx + (size_t)ROWS * KN);
    ushort_t* pooled_b = xh;                         // alias

    prep_kernel<<<ROWS / 4, 256, 0, stream>>>(feats, xh, norms);
    prepw_kernel<<<(512 * 512) / (256 * 8), 256, 0, stream>>>(fc_w, fcw_b);

    simtop_kernel<<<(ROWS / BR) * SPLITS, 256, 0, stream>>>(xh, cand);

    refine_kernel<<<ROWS / 4, 256, 0, stream>>>(feats, norms, cand, idx);

    convmap_kernel<<<ROWS / 4, 256, 0, stream>>>(feats, convKK_w, convKK_b, idx, pooled_b);

    dim3 gF(ROWS / 128, 512 / 128);
    fc_mfma_kernel<<<gF, 256, 0, stream>>>(fcw_b, pooled_b, out);
}